// Round 11
// baseline (413.286 us; speedup 1.0000x reference)
//
#include <hip/hip_runtime.h>

#define Bq 2
#define Lq 2048
#define Dq 1024
#define Hq 16
#define HDq 64

typedef _Float16 f16;
typedef _Float16 f16x8 __attribute__((ext_vector_type(8)));
typedef _Float16 f16x4 __attribute__((ext_vector_type(4)));
typedef __fp16 hf16x2 __attribute__((ext_vector_type(2)));
typedef float f32x4 __attribute__((ext_vector_type(4)));
typedef float f32x16 __attribute__((ext_vector_type(16)));

__device__ __forceinline__ void gload_lds16(const void* g, void* l) {
    __builtin_amdgcn_global_load_lds(
        (const __attribute__((address_space(1))) unsigned int*)g,
        (__attribute__((address_space(3))) unsigned int*)l, 16, 0, 0);
}

__device__ __forceinline__ void swap32(int& a, int& b) {
    asm volatile("v_permlane32_swap_b32 %0, %1" : "+v"(a), "+v"(b));
}

__device__ __forceinline__ int pk2(float a, float b) {
    hf16x2 v = __builtin_amdgcn_cvt_pkrtz(a, b);
    return __builtin_bit_cast(int, v);
}

// ---------------- fp32 -> fp16 conversion ------------------------------------
__global__ __launch_bounds__(256) void convert_kernel(
    const float* __restrict__ x,
    const float* __restrict__ wq, const float* __restrict__ wk, const float* __restrict__ wv,
    f16* __restrict__ x_h, f16* __restrict__ wq_h, f16* __restrict__ wk_h, f16* __restrict__ wv_h)
{
    const int NX = Bq*Lq*Dq;
    const int NW = Dq*Dq;
    const int total4 = (NX + 3*NW) / 4;
    for (int i = blockIdx.x*blockDim.x + threadIdx.x; i < total4;
         i += gridDim.x*blockDim.x) {
        int e = i * 4;
        const float* src; f16* dst; int off;
        if (e < NX) { src = x; dst = x_h; off = e; }
        else {
            int t = e - NX; int w = t >> 20; off = t & (NW-1);
            src = (w==0) ? wq : (w==1) ? wk : wv;
            dst = (w==0) ? wq_h : (w==1) ? wk_h : wv_h;
        }
        float4 v = *reinterpret_cast<const float4*>(src + off);
        f16x4 hv; hv.x=(f16)v.x; hv.y=(f16)v.y; hv.z=(f16)v.z; hv.w=(f16)v.w;
        *reinterpret_cast<f16x4*>(dst + off) = hv;
    }
}

// ---------------- QKV projection, fp16 MFMA ----------------------------------
#define GBM 128
#define GBN 128
#define GBK 32

__global__ __launch_bounds__(256) void qkv_mfma_kernel(
    const f16* __restrict__ x_h,
    const f16* __restrict__ wq_h, const f16* __restrict__ wk_h, const f16* __restrict__ wv_h,
    f16* __restrict__ q_h, f16* __restrict__ k_h, f16* __restrict__ vT_h)
{
    __shared__ __align__(16) f16 As[GBM*GBK];
    __shared__ __align__(16) f16 Bs[GBN*GBK];

    const int tid  = threadIdx.x;
    const int lane = tid & 63;
    const int wave = tid >> 6;
    const int wr = wave >> 1, wc = wave & 1;
    const int l15 = lane & 15, l4 = lane >> 4;
    const int n0 = blockIdx.x * GBN;
    const int m0 = blockIdx.y * GBM;
    const int z  = blockIdx.z;
    const f16* W = (z==0) ? wq_h : (z==1) ? wk_h : wv_h;

    const int sslot = tid & 3;

    f32x4 acc[4][4];
    #pragma unroll
    for (int i=0;i<4;++i)
        #pragma unroll
        for (int j=0;j<4;++j) acc[i][j] = f32x4{0.f,0.f,0.f,0.f};

    for (int kt = 0; kt < Dq; kt += GBK) {
        __syncthreads();
        #pragma unroll
        for (int j = 0; j < 2; ++j) {
            int slotIdx = tid + j*256;
            int row = slotIdx >> 2;
            gload_lds16(x_h + (size_t)(m0+row)*Dq + kt + sslot*8,
                        (char*)As + slotIdx*16);
            gload_lds16(W   + (size_t)(n0+row)*Dq + kt + sslot*8,
                        (char*)Bs + slotIdx*16);
        }
        __syncthreads();

        f16x8 a[4], b[4];
        #pragma unroll
        for (int m=0;m<4;++m) {
            int row = wr*64 + m*16 + l15;
            a[m] = *reinterpret_cast<const f16x8*>((const char*)As + row*64 + l4*16);
        }
        #pragma unroll
        for (int n=0;n<4;++n) {
            int row = wc*64 + n*16 + l15;
            b[n] = *reinterpret_cast<const f16x8*>((const char*)Bs + row*64 + l4*16);
        }
        #pragma unroll
        for (int m=0;m<4;++m)
            #pragma unroll
            for (int n=0;n<4;++n)
                acc[m][n] = __builtin_amdgcn_mfma_f32_16x16x32_f16(a[m], b[n], acc[m][n], 0,0,0);
    }

    #pragma unroll
    for (int m=0;m<4;++m) {
        #pragma unroll
        for (int r=0;r<4;++r) {
            int grow = m0 + wr*64 + m*16 + l4*4 + r;
            int b_   = grow >> 11;
            int lrow = grow & (Lq-1);
            #pragma unroll
            for (int n=0;n<4;++n) {
                int gcol = n0 + wc*64 + n*16 + l15;
                int h = gcol >> 6, d = gcol & 63;
                int bh = b_*Hq + h;
                f16 val = (f16)acc[m][n][r];
                if (z==0)      q_h[((size_t)bh*Lq + lrow)*HDq + d] = val;
                else if (z==1) k_h[((size_t)bh*Lq + lrow)*HDq + d] = val;
                else           vT_h[((size_t)bh*HDq + d)*Lq + lrow] = val;
            }
        }
    }
}

// ---------------- quantum -> 8x, f32, MFMA-C-fragment order ------------------
__global__ __launch_bounds__(256) void qm_pre_kernel(
    const float* __restrict__ quantum, float* __restrict__ qm_pre)
{
    __shared__ float qs[32][65];
    const int tid = threadIdx.x;
    const int qt = blockIdx.x, t = blockIdx.y, b = blockIdx.z;
    const float* base = quantum + ((size_t)b*Lq + qt*32)*Lq + t*64;
    #pragma unroll
    for (int i=0;i<2;++i) {
        int idx = tid + i*256;
        int r = idx >> 4, c = (idx & 15)*4;
        float4 v = *reinterpret_cast<const float4*>(base + (size_t)r*Lq + c);
        qs[r][c+0]=v.x*8.f; qs[r][c+1]=v.y*8.f; qs[r][c+2]=v.z*8.f; qs[r][c+3]=v.w*8.f;
    }
    __syncthreads();
    float* outb = qm_pre + (((size_t)b*32 + t)*64 + qt)*2048;
    #pragma unroll
    for (int i=0;i<2;++i) {
        int g = tid + i*256;
        int kt = g >> 8;
        int j  = (g >> 6) & 3;
        int lane = g & 63;
        int l31 = lane & 31, hi = lane >> 5;
        int col = kt*32 + 8*j + 4*hi;
        float4 v = { qs[l31][col], qs[l31][col+1], qs[l31][col+2], qs[l31][col+3] };
        *reinterpret_cast<float4*>(outb + ((size_t)kt*4 + j)*256 + lane*4) = v;
    }
}

// ---------------- flash attention, split-KV, 32KB double-buffered LDS --------
__global__ __launch_bounds__(256, 4) void attn4_kernel(
    const f16* __restrict__ q_h, const f16* __restrict__ k_h, const f16* __restrict__ vT_h,
    const float* __restrict__ qm_pre, const float* __restrict__ scale,
    f16* __restrict__ oP, float* __restrict__ tP)
{
    __shared__ __align__(16) char lds[32768];   // 2 bufs x [K 8KB | V 8KB]

    const int tid  = threadIdx.x;
    const int lane = tid & 63;
    const int wave = tid >> 6;          // 0..3
    const int l31  = lane & 31;
    const int hi   = lane >> 5;
    const int bh = blockIdx.x;
    const int qb = blockIdx.y;
    const int z  = blockIdx.z;          // KV split: tiles [z*16, z*16+16)
    const int z16 = z*16;
    const int b_ = bh >> 4, h = bh & 15;
    const int qW = qb*128 + wave*32;
    const int qt = qb*4 + wave;
    const float c1 = 0.125f * scale[h] * 1.44269504f;
    const bool pos = (c1 >= 0.f);

    const f16* kbase = k_h  + (size_t)bh*Lq*HDq;
    const f16* vbase = vT_h + (size_t)bh*HDq*Lq;

    f16x8 qf[4];
    {
        const f16* qb_ = q_h + ((size_t)bh*Lq + qW + l31)*HDq + hi*8;
        #pragma unroll
        for (int ds=0; ds<4; ++ds)
            qf[ds] = *reinterpret_cast<const f16x8*>(qb_ + ds*16);
    }

    f32x16 o0, o1;
    #pragma unroll
    for (int r=0;r<16;++r) { o0[r]=0.f; o1[r]=0.f; }
    float m_run = pos ? -1e30f : 1e30f;
    float s_run = 0.f;

    auto STAGE = [&](int t, int buf) {   // t local (0..15); tile t -> buf t&1
        const int k0 = (z16 + t)*64;
        char* LK = lds + buf*16384;
        char* LV = LK + 8192;
        #pragma unroll
        for (int i=0;i<2;++i) {
            int g = tid + i*256;
            int row = g >> 3, slot = g & 7;
            int ss = slot ^ (row & 7);
            gload_lds16(kbase + (size_t)(k0+row)*HDq + ss*8, LK + g*16);
            gload_lds16(vbase + (size_t)row*Lq + k0 + ss*8,  LV + g*16);
        }
    };

    auto QMLOAD = [&](int t, f32x4 (&qm)[2][4]) {  // t local
        const char* qmb = (const char*)qm_pre
            + ((((size_t)b_*32 + z16 + t)*64 + qt)*2048)*4 + lane*16;
        #pragma unroll
        for (int kt=0;kt<2;++kt)
            #pragma unroll
            for (int j=0;j<4;++j)
                qm[kt][j] = *reinterpret_cast<const f32x4*>(qmb + kt*4096 + j*1024);
    };

    auto COMPUTE = [&](int t, int buf, f32x4 (&qmc)[2][4], f32x4 (&qmn)[2][4]) {
        const char* LK = lds + buf*16384;
        const char* LV = LK + 8192;
        int tn = (t+1 < 16) ? t+1 : 15;
        QMLOAD(tn, qmn);

        // y = K Q^T + 8*quantum (bias via accumulator init)
        f32x16 st[2];
        #pragma unroll
        for (int kt=0;kt<2;++kt)
            #pragma unroll
            for (int j=0;j<4;++j)
                #pragma unroll
                for (int c=0;c<4;++c) st[kt][4*j+c] = qmc[kt][j][c];
        __builtin_amdgcn_s_setprio(1);
        #pragma unroll
        for (int kt=0;kt<2;++kt) {
            #pragma unroll
            for (int ds=0;ds<4;++ds) {
                f16x8 ka = *reinterpret_cast<const f16x8*>(
                    LK + ((kt*32+l31)<<7) + (((ds*2+hi)^(l31&7))<<4));
                st[kt] = __builtin_amdgcn_mfma_f32_32x32x16_f16(ka, qf[ds], st[kt], 0,0,0);
            }
        }
        __builtin_amdgcn_s_setprio(0);

        // tile extremum (max if c1>=0 else min)
        float text;
        {
            float w_[16];
            if (pos) {
                #pragma unroll
                for (int r=0;r<16;++r) w_[r] = fmaxf(st[0][r], st[1][r]);
                #pragma unroll
                for (int w=8; w>0; w>>=1)
                    #pragma unroll
                    for (int r=0;r<w;++r) w_[r] = fmaxf(w_[r], w_[r+w]);
                text = fmaxf(w_[0], __shfl_xor(w_[0], 32));
            } else {
                #pragma unroll
                for (int r=0;r<16;++r) w_[r] = fminf(st[0][r], st[1][r]);
                #pragma unroll
                for (int w=8; w>0; w>>=1)
                    #pragma unroll
                    for (int r=0;r<w;++r) w_[r] = fminf(w_[r], w_[r+w]);
                text = fminf(w_[0], __shfl_xor(w_[0], 32));
            }
        }

        float u = c1*(text - m_run);
        if (!__all(u <= 8.f)) {
            float m_new = pos ? fmaxf(m_run, text) : fminf(m_run, text);
            float corr = __builtin_amdgcn_exp2f(c1*(m_run - m_new));
            m_run = m_new;
            s_run *= corr;
            #pragma unroll
            for (int r=0;r<16;++r) { o0[r] *= corr; o1[r] *= corr; }
        }

        float mb = c1 * m_run;
        float p[32];
        #pragma unroll
        for (int r=0;r<16;++r) {
            p[r]    = __builtin_amdgcn_exp2f(__builtin_fmaf(st[0][r], c1, -mb));
            p[16+r] = __builtin_amdgcn_exp2f(__builtin_fmaf(st[1][r], c1, -mb));
        }
        float sm[16];
        #pragma unroll
        for (int r=0;r<16;++r) sm[r] = p[r] + p[r+16];
        #pragma unroll
        for (int w=8; w>0; w>>=1)
            #pragma unroll
            for (int r=0;r<w;++r) sm[r] += sm[r+w];
        s_run += sm[0];

        f16x8 pb[4];
        #pragma unroll
        for (int ks=0; ks<4; ++ks) {
            int w0 = pk2(p[8*ks+0], p[8*ks+1]);
            int w1 = pk2(p[8*ks+2], p[8*ks+3]);
            int w2 = pk2(p[8*ks+4], p[8*ks+5]);
            int w3 = pk2(p[8*ks+6], p[8*ks+7]);
            swap32(w0, w2);
            swap32(w1, w3);
            union { int w[4]; f16x8 v; } u2;
            u2.w[0]=w0; u2.w[1]=w1; u2.w[2]=w2; u2.w[3]=w3;
            pb[ks] = u2.v;
        }

        __builtin_amdgcn_s_setprio(1);
        #pragma unroll
        for (int ks=0; ks<4; ++ks) {
            f16x8 va0 = *reinterpret_cast<const f16x8*>(
                LV + (l31<<7)        + (((ks*2+hi)^(l31&7))<<4));
            f16x8 va1 = *reinterpret_cast<const f16x8*>(
                LV + ((32+l31)<<7)   + (((ks*2+hi)^(l31&7))<<4));
            o0 = __builtin_amdgcn_mfma_f32_32x32x16_f16(va0, pb[ks], o0, 0,0,0);
            o1 = __builtin_amdgcn_mfma_f32_32x32x16_f16(va1, pb[ks], o1, 0,0,0);
        }
        __builtin_amdgcn_s_setprio(0);
    };

    f32x4 qmE[2][4], qmO[2][4];

    // prologue: QM(0) then STAGE(0)
    QMLOAD(0, qmE);
    STAGE(0, 0);

    #define VMW(n) asm volatile("s_waitcnt vmcnt(" #n ")" ::: "memory")

    // 2-buffer, 1 barrier/iter. Tile t ALWAYS lives in buf t&1.
    // At iter-t barrier all waves finished COMPUTE(t-1)'s reads of
    // buf[(t+1)&1], so STAGE(t+1) may overwrite it immediately.
    // vmcnt before barrier: younger-than-STAGE(t) = QM(t+1) prefetch = 8
    // (t=0: nothing younger -> 0).
    VMW(0); __builtin_amdgcn_s_barrier();
    STAGE(1, 1); COMPUTE(0, 0, qmE, qmO);
    for (int t = 1; t < 15; t += 2) {
        // t odd -> buf 1; t+1 even -> buf 0
        VMW(8); __builtin_amdgcn_s_barrier();
        STAGE(t+1, 0); COMPUTE(t, 1, qmO, qmE);
        VMW(8); __builtin_amdgcn_s_barrier();
        STAGE(t+2, 1); COMPUTE(t+1, 0, qmE, qmO);
    }
    // t = 15 (odd, buf 1): no further stage
    VMW(8); __builtin_amdgcn_s_barrier();
    COMPUTE(15, 1, qmO, qmE);

    #undef VMW

    // epilogue: s-normalized partial O (f16) + log-domain weight
    float s_tot = s_run + __shfl_xor(s_run, 32);
    float inv = 1.0f / s_tot;
    f16* obp = oP + ((size_t)(z*32 + bh)*Lq + qW + l31)*64;
    #pragma unroll
    for (int r=0;r<16;++r) {
        int drow = (r&3) + 8*(r>>2) + 4*hi;
        obp[drow]      = (f16)(o0[r]*inv);
        obp[32 + drow] = (f16)(o1[r]*inv);
    }
    if (hi == 0)
        tP[(size_t)(z*32 + bh)*Lq + qW + l31] =
            c1*m_run + __builtin_amdgcn_logf(s_tot);   // v_log_f32 = log2
}

// ---------------- combine the two KV halves ----------------------------------
__global__ __launch_bounds__(256) void combine_kernel(
    const f16* __restrict__ oP, const float* __restrict__ tP,
    float* __restrict__ out)
{
    const int tid = threadIdx.x;
    const int bh = blockIdx.x, rt = blockIdx.y;
    const int b_ = bh >> 4, h = bh & 15;
    const int row = rt*128 + (tid >> 1);
    const int dh = (tid & 1)*32;
    const size_t r0 = (size_t)bh*Lq + row;
    const size_t zr = (size_t)32*Lq;

    float t0 = tP[r0], t1 = tP[zr + r0];
    float T = fmaxf(t0, t1);
    float w0 = __builtin_amdgcn_exp2f(t0 - T);
    float w1 = __builtin_amdgcn_exp2f(t1 - T);
    float inv = 1.0f/(w0 + w1);
    w0 *= inv; w1 *= inv;

    const f16* p0 = oP + r0*64 + dh;
    const f16* p1 = oP + zr*64 + r0*64 + dh;
    float* op = out + ((size_t)b_*Lq + row)*Dq + h*HDq + dh;
    #pragma unroll
    for (int j=0;j<4;++j) {
        f16x8 a = *reinterpret_cast<const f16x8*>(p0 + j*8);
        f16x8 b = *reinterpret_cast<const f16x8*>(p1 + j*8);
        float4 v0, v1;
        v0.x = (float)a[0]*w0 + (float)b[0]*w1;
        v0.y = (float)a[1]*w0 + (float)b[1]*w1;
        v0.z = (float)a[2]*w0 + (float)b[2]*w1;
        v0.w = (float)a[3]*w0 + (float)b[3]*w1;
        v1.x = (float)a[4]*w0 + (float)b[4]*w1;
        v1.y = (float)a[5]*w0 + (float)b[5]*w1;
        v1.z = (float)a[6]*w0 + (float)b[6]*w1;
        v1.w = (float)a[7]*w0 + (float)b[7]*w1;
        *reinterpret_cast<float4*>(op + j*8)     = v0;
        *reinterpret_cast<float4*>(op + j*8 + 4) = v1;
    }
}

extern "C" void kernel_launch(void* const* d_in, const int* in_sizes, int n_in,
                              void* d_out, int out_size, void* d_ws, size_t ws_size,
                              hipStream_t stream) {
    const float* x       = (const float*)d_in[0];
    const float* quantum = (const float*)d_in[1];
    const float* wq      = (const float*)d_in[2];
    const float* wk      = (const float*)d_in[3];
    const float* wv      = (const float*)d_in[4];
    const float* scale   = (const float*)d_in[5];
    float* out = (float*)d_out;

    f16* ws     = (f16*)d_ws;
    f16* x_h    = ws;
    f16* wq_h   = ws + 4194304;
    f16* wk_h   = ws + 5242880;
    f16* wv_h   = ws + 6291456;
    f16* q_h    = ws + 7340032;
    f16* k_h    = ws + 11534336;
    f16* vT_h   = ws + 15728640;
    float* qm32 = (float*)(ws + 19922944);   // 8,388,608 f32
    f16* oP     = ws + 36700160;             // 8,388,608 f16 (2 z-halves)
    float* tP   = (float*)(ws + 45088768);   // 131,072 f32

    convert_kernel<<<1024, 256, 0, stream>>>(x, wq, wk, wv, x_h, wq_h, wk_h, wv_h);

    dim3 gq(64, 32, 2);
    qm_pre_kernel<<<gq, 256, 0, stream>>>(quantum, qm32);

    dim3 g1(Dq/GBN, (Bq*Lq)/GBM, 3);
    qkv_mfma_kernel<<<g1, 256, 0, stream>>>(x_h, wq_h, wk_h, wv_h, q_h, k_h, vT_h);

    dim3 g2(Bq*Hq, Lq/128, 2);
    attn4_kernel<<<g2, 256, 0, stream>>>(q_h, k_h, vT_h, qm32, scale, oP, tP);

    dim3 g3(Bq*Hq, Lq/128);
    combine_kernel<<<g3, 256, 0, stream>>>(oP, tP, out);
}

// Round 12
// 197.522 us; speedup vs baseline: 2.0924x; 2.0924x over previous
//
#include <hip/hip_runtime.h>

#define Bq 2
#define Lq 2048
#define Dq 1024
#define Hq 16
#define HDq 64

typedef _Float16 f16;
typedef _Float16 f16x8 __attribute__((ext_vector_type(8)));
typedef _Float16 f16x4 __attribute__((ext_vector_type(4)));
typedef __fp16 hf16x2 __attribute__((ext_vector_type(2)));
typedef float f32x4 __attribute__((ext_vector_type(4)));
typedef float f32x16 __attribute__((ext_vector_type(16)));

__device__ __forceinline__ void gload_lds16(const void* g, void* l) {
    __builtin_amdgcn_global_load_lds(
        (const __attribute__((address_space(1))) unsigned int*)g,
        (__attribute__((address_space(3))) unsigned int*)l, 16, 0, 0);
}

__device__ __forceinline__ void swap32(int& a, int& b) {
    asm volatile("v_permlane32_swap_b32 %0, %1" : "+v"(a), "+v"(b));
}

__device__ __forceinline__ int pk2(float a, float b) {
    hf16x2 v = __builtin_amdgcn_cvt_pkrtz(a, b);
    return __builtin_bit_cast(int, v);
}

// ---------------- fp32 -> fp16 conversion ------------------------------------
__global__ __launch_bounds__(256) void convert_kernel(
    const float* __restrict__ x,
    const float* __restrict__ wq, const float* __restrict__ wk, const float* __restrict__ wv,
    f16* __restrict__ x_h, f16* __restrict__ wq_h, f16* __restrict__ wk_h, f16* __restrict__ wv_h)
{
    const int NX = Bq*Lq*Dq;
    const int NW = Dq*Dq;
    const int total4 = (NX + 3*NW) / 4;
    for (int i = blockIdx.x*blockDim.x + threadIdx.x; i < total4;
         i += gridDim.x*blockDim.x) {
        int e = i * 4;
        const float* src; f16* dst; int off;
        if (e < NX) { src = x; dst = x_h; off = e; }
        else {
            int t = e - NX; int w = t >> 20; off = t & (NW-1);
            src = (w==0) ? wq : (w==1) ? wk : wv;
            dst = (w==0) ? wq_h : (w==1) ? wk_h : wv_h;
        }
        float4 v = *reinterpret_cast<const float4*>(src + off);
        f16x4 hv; hv.x=(f16)v.x; hv.y=(f16)v.y; hv.z=(f16)v.z; hv.w=(f16)v.w;
        *reinterpret_cast<f16x4*>(dst + off) = hv;
    }
}

// ---------------- QKV projection, fp16 MFMA ----------------------------------
#define GBM 128
#define GBN 128
#define GBK 32

__global__ __launch_bounds__(256) void qkv_mfma_kernel(
    const f16* __restrict__ x_h,
    const f16* __restrict__ wq_h, const f16* __restrict__ wk_h, const f16* __restrict__ wv_h,
    f16* __restrict__ q_h, f16* __restrict__ k_h, f16* __restrict__ vT_h)
{
    __shared__ __align__(16) f16 As[GBM*GBK];
    __shared__ __align__(16) f16 Bs[GBN*GBK];

    const int tid  = threadIdx.x;
    const int lane = tid & 63;
    const int wave = tid >> 6;
    const int wr = wave >> 1, wc = wave & 1;
    const int l15 = lane & 15, l4 = lane >> 4;
    const int n0 = blockIdx.x * GBN;
    const int m0 = blockIdx.y * GBM;
    const int z  = blockIdx.z;
    const f16* W = (z==0) ? wq_h : (z==1) ? wk_h : wv_h;

    const int sslot = tid & 3;

    f32x4 acc[4][4];
    #pragma unroll
    for (int i=0;i<4;++i)
        #pragma unroll
        for (int j=0;j<4;++j) acc[i][j] = f32x4{0.f,0.f,0.f,0.f};

    for (int kt = 0; kt < Dq; kt += GBK) {
        __syncthreads();
        #pragma unroll
        for (int j = 0; j < 2; ++j) {
            int slotIdx = tid + j*256;
            int row = slotIdx >> 2;
            gload_lds16(x_h + (size_t)(m0+row)*Dq + kt + sslot*8,
                        (char*)As + slotIdx*16);
            gload_lds16(W   + (size_t)(n0+row)*Dq + kt + sslot*8,
                        (char*)Bs + slotIdx*16);
        }
        __syncthreads();

        f16x8 a[4], b[4];
        #pragma unroll
        for (int m=0;m<4;++m) {
            int row = wr*64 + m*16 + l15;
            a[m] = *reinterpret_cast<const f16x8*>((const char*)As + row*64 + l4*16);
        }
        #pragma unroll
        for (int n=0;n<4;++n) {
            int row = wc*64 + n*16 + l15;
            b[n] = *reinterpret_cast<const f16x8*>((const char*)Bs + row*64 + l4*16);
        }
        #pragma unroll
        for (int m=0;m<4;++m)
            #pragma unroll
            for (int n=0;n<4;++n)
                acc[m][n] = __builtin_amdgcn_mfma_f32_16x16x32_f16(a[m], b[n], acc[m][n], 0,0,0);
    }

    #pragma unroll
    for (int m=0;m<4;++m) {
        #pragma unroll
        for (int r=0;r<4;++r) {
            int grow = m0 + wr*64 + m*16 + l4*4 + r;
            int b_   = grow >> 11;
            int lrow = grow & (Lq-1);
            #pragma unroll
            for (int n=0;n<4;++n) {
                int gcol = n0 + wc*64 + n*16 + l15;
                int h = gcol >> 6, d = gcol & 63;
                int bh = b_*Hq + h;
                f16 val = (f16)acc[m][n][r];
                if (z==0)      q_h[((size_t)bh*Lq + lrow)*HDq + d] = val;
                else if (z==1) k_h[((size_t)bh*Lq + lrow)*HDq + d] = val;
                else           vT_h[((size_t)bh*HDq + d)*Lq + lrow] = val;
            }
        }
    }
}

// ---------------- quantum -> 8x, f32, MFMA-C-fragment order ------------------
__global__ __launch_bounds__(256) void qm_pre_kernel(
    const float* __restrict__ quantum, float* __restrict__ qm_pre)
{
    __shared__ float qs[32][65];
    const int tid = threadIdx.x;
    const int qt = blockIdx.x, t = blockIdx.y, b = blockIdx.z;
    const float* base = quantum + ((size_t)b*Lq + qt*32)*Lq + t*64;
    #pragma unroll
    for (int i=0;i<2;++i) {
        int idx = tid + i*256;
        int r = idx >> 4, c = (idx & 15)*4;
        float4 v = *reinterpret_cast<const float4*>(base + (size_t)r*Lq + c);
        qs[r][c+0]=v.x*8.f; qs[r][c+1]=v.y*8.f; qs[r][c+2]=v.z*8.f; qs[r][c+3]=v.w*8.f;
    }
    __syncthreads();
    float* outb = qm_pre + (((size_t)b*32 + t)*64 + qt)*2048;
    #pragma unroll
    for (int i=0;i<2;++i) {
        int g = tid + i*256;
        int kt = g >> 8;
        int j  = (g >> 6) & 3;
        int lane = g & 63;
        int l31 = lane & 31, hi = lane >> 5;
        int col = kt*32 + 8*j + 4*hi;
        float4 v = { qs[l31][col], qs[l31][col+1], qs[l31][col+2], qs[l31][col+3] };
        *reinterpret_cast<float4*>(outb + ((size_t)kt*4 + j)*256 + lane*4) = v;
    }
}

// ---------------- flash attention, split-KV, reg-lean COMPUTE ----------------
__global__ __launch_bounds__(256, 3) void attn4_kernel(
    const f16* __restrict__ q_h, const f16* __restrict__ k_h, const f16* __restrict__ vT_h,
    const float* __restrict__ qm_pre, const float* __restrict__ scale,
    f16* __restrict__ oP, float* __restrict__ tP)
{
    __shared__ __align__(16) char lds[32768];   // 2 bufs x [K 8KB | V 8KB]

    const int tid  = threadIdx.x;
    const int lane = tid & 63;
    const int wave = tid >> 6;          // 0..3
    const int l31  = lane & 31;
    const int hi   = lane >> 5;
    const int bh = blockIdx.x;
    const int qb = blockIdx.y;
    const int z  = blockIdx.z;          // KV split: tiles [z*16, z*16+16)
    const int z16 = z*16;
    const int b_ = bh >> 4, h = bh & 15;
    const int qW = qb*128 + wave*32;
    const int qt = qb*4 + wave;
    const float c1 = 0.125f * scale[h] * 1.44269504f;
    const bool pos = (c1 >= 0.f);

    const f16* kbase = k_h  + (size_t)bh*Lq*HDq;
    const f16* vbase = vT_h + (size_t)bh*HDq*Lq;

    f16x8 qf[4];
    {
        const f16* qb_ = q_h + ((size_t)bh*Lq + qW + l31)*HDq + hi*8;
        #pragma unroll
        for (int ds=0; ds<4; ++ds)
            qf[ds] = *reinterpret_cast<const f16x8*>(qb_ + ds*16);
    }

    f32x16 o0, o1;
    #pragma unroll
    for (int r=0;r<16;++r) { o0[r]=0.f; o1[r]=0.f; }
    float m_run = pos ? -1e30f : 1e30f;
    float s_run = 0.f;

    auto STAGE = [&](int t, int buf) {   // t local (0..15); tile t -> buf t&1
        const int k0 = (z16 + t)*64;
        char* LK = lds + buf*16384;
        char* LV = LK + 8192;
        #pragma unroll
        for (int i=0;i<2;++i) {
            int g = tid + i*256;
            int row = g >> 3, slot = g & 7;
            int ss = slot ^ (row & 7);
            gload_lds16(kbase + (size_t)(k0+row)*HDq + ss*8, LK + g*16);
            gload_lds16(vbase + (size_t)row*Lq + k0 + ss*8,  LV + g*16);
        }
    };

    auto QMLOAD = [&](int t, f32x4 (&qm)[2][4]) {  // t local
        const char* qmb = (const char*)qm_pre
            + ((((size_t)b_*32 + z16 + t)*64 + qt)*2048)*4 + lane*16;
        #pragma unroll
        for (int kt=0;kt<2;++kt)
            #pragma unroll
            for (int j=0;j<4;++j)
                qm[kt][j] = *reinterpret_cast<const f32x4*>(qmb + kt*4096 + j*1024);
    };

    auto COMPUTE = [&](int t, int buf, f32x4 (&qmc)[2][4], f32x4 (&qmn)[2][4]) {
        const char* LK = lds + buf*16384;
        const char* LV = LK + 8192;
        int tn = (t+1 < 16) ? t+1 : 15;
        QMLOAD(tn, qmn);

        // y = K Q^T + 8*quantum (bias via accumulator init)
        f32x16 st[2];
        #pragma unroll
        for (int kt=0;kt<2;++kt)
            #pragma unroll
            for (int j=0;j<4;++j)
                #pragma unroll
                for (int c=0;c<4;++c) st[kt][4*j+c] = qmc[kt][j][c];
        __builtin_amdgcn_s_setprio(1);
        #pragma unroll
        for (int kt=0;kt<2;++kt) {
            #pragma unroll
            for (int ds=0;ds<4;++ds) {
                f16x8 ka = *reinterpret_cast<const f16x8*>(
                    LK + ((kt*32+l31)<<7) + (((ds*2+hi)^(l31&7))<<4));
                st[kt] = __builtin_amdgcn_mfma_f32_32x32x16_f16(ka, qf[ds], st[kt], 0,0,0);
            }
        }
        __builtin_amdgcn_s_setprio(0);

        // tile extremum (max if c1>=0 else min; block-uniform branch)
        float text;
        {
            float w_[16];
            if (pos) {
                #pragma unroll
                for (int r=0;r<16;++r) w_[r] = fmaxf(st[0][r], st[1][r]);
                #pragma unroll
                for (int w=8; w>0; w>>=1)
                    #pragma unroll
                    for (int r=0;r<w;++r) w_[r] = fmaxf(w_[r], w_[r+w]);
                text = fmaxf(w_[0], __shfl_xor(w_[0], 32));
            } else {
                #pragma unroll
                for (int r=0;r<16;++r) w_[r] = fminf(st[0][r], st[1][r]);
                #pragma unroll
                for (int w=8; w>0; w>>=1)
                    #pragma unroll
                    for (int r=0;r<w;++r) w_[r] = fminf(w_[r], w_[r+w]);
                text = fminf(w_[0], __shfl_xor(w_[0], 32));
            }
        }

        float u = c1*(text - m_run);
        if (!__all(u <= 8.f)) {
            float m_new = pos ? fmaxf(m_run, text) : fminf(m_run, text);
            float corr = __builtin_amdgcn_exp2f(c1*(m_run - m_new));
            m_run = m_new;
            s_run *= corr;
            #pragma unroll
            for (int r=0;r<16;++r) { o0[r] *= corr; o1[r] *= corr; }
        }

        // P = 2^(c1*y - c1*m) IN PLACE on st (frees 32 regs vs separate p[])
        float mb = c1 * m_run;
        #pragma unroll
        for (int kt=0;kt<2;++kt)
            #pragma unroll
            for (int r=0;r<16;++r)
                st[kt][r] = __builtin_amdgcn_exp2f(__builtin_fmaf(st[kt][r], c1, -mb));

        // sum tree directly from st
        float sm[8];
        #pragma unroll
        for (int r=0;r<8;++r)
            sm[r] = (st[0][r] + st[0][r+8]) + (st[1][r] + st[1][r+8]);
        #pragma unroll
        for (int w=4; w>0; w>>=1)
            #pragma unroll
            for (int r=0;r<w;++r) sm[r] += sm[r+w];
        s_run += sm[0];

        // pack + PV fused per ks (no pb[] staging)
        __builtin_amdgcn_s_setprio(1);
        #pragma unroll
        for (int ks=0; ks<4; ++ks) {
            const int si = ks >> 1, base = (ks & 1)*8;
            int w0 = pk2(st[si][base+0], st[si][base+1]);
            int w1 = pk2(st[si][base+2], st[si][base+3]);
            int w2 = pk2(st[si][base+4], st[si][base+5]);
            int w3 = pk2(st[si][base+6], st[si][base+7]);
            swap32(w0, w2);
            swap32(w1, w3);
            union { int w[4]; f16x8 v; } u2;
            u2.w[0]=w0; u2.w[1]=w1; u2.w[2]=w2; u2.w[3]=w3;
            f16x8 va0 = *reinterpret_cast<const f16x8*>(
                LV + (l31<<7)        + (((ks*2+hi)^(l31&7))<<4));
            f16x8 va1 = *reinterpret_cast<const f16x8*>(
                LV + ((32+l31)<<7)   + (((ks*2+hi)^(l31&7))<<4));
            o0 = __builtin_amdgcn_mfma_f32_32x32x16_f16(va0, u2.v, o0, 0,0,0);
            o1 = __builtin_amdgcn_mfma_f32_32x32x16_f16(va1, u2.v, o1, 0,0,0);
        }
        __builtin_amdgcn_s_setprio(0);
    };

    f32x4 qmE[2][4], qmO[2][4];

    // prologue: QM(0) then STAGE(0)
    QMLOAD(0, qmE);
    STAGE(0, 0);

    #define VMW(n) asm volatile("s_waitcnt vmcnt(" #n ")" ::: "memory")

    // 2-buffer, 1 barrier/iter. Tile t ALWAYS lives in buf t&1.
    // At iter-t barrier all waves finished COMPUTE(t-1)'s reads of
    // buf[(t+1)&1], so STAGE(t+1) may overwrite it immediately.
    // vmcnt before barrier: younger-than-STAGE(t) = QM(t+1) prefetch = 8.
    VMW(0); __builtin_amdgcn_s_barrier();
    STAGE(1, 1); COMPUTE(0, 0, qmE, qmO);
    for (int t = 1; t < 15; t += 2) {
        VMW(8); __builtin_amdgcn_s_barrier();
        STAGE(t+1, 0); COMPUTE(t, 1, qmO, qmE);
        VMW(8); __builtin_amdgcn_s_barrier();
        STAGE(t+2, 1); COMPUTE(t+1, 0, qmE, qmO);
    }
    VMW(8); __builtin_amdgcn_s_barrier();
    COMPUTE(15, 1, qmO, qmE);

    #undef VMW

    // epilogue: s-normalized partial O (f16) + log-domain weight
    float s_tot = s_run + __shfl_xor(s_run, 32);
    float inv = 1.0f / s_tot;
    f16* obp = oP + ((size_t)(z*32 + bh)*Lq + qW + l31)*64;
    #pragma unroll
    for (int r=0;r<16;++r) {
        int drow = (r&3) + 8*(r>>2) + 4*hi;
        obp[drow]      = (f16)(o0[r]*inv);
        obp[32 + drow] = (f16)(o1[r]*inv);
    }
    if (hi == 0)
        tP[(size_t)(z*32 + bh)*Lq + qW + l31] =
            c1*m_run + __builtin_amdgcn_logf(s_tot);   // v_log_f32 = log2
}

// ---------------- combine the two KV halves ----------------------------------
__global__ __launch_bounds__(256) void combine_kernel(
    const f16* __restrict__ oP, const float* __restrict__ tP,
    float* __restrict__ out)
{
    const int tid = threadIdx.x;
    const int bh = blockIdx.x, rt = blockIdx.y;
    const int b_ = bh >> 4, h = bh & 15;
    const int row = rt*128 + (tid >> 1);
    const int dh = (tid & 1)*32;
    const size_t r0 = (size_t)bh*Lq + row;
    const size_t zr = (size_t)32*Lq;

    float t0 = tP[r0], t1 = tP[zr + r0];
    float T = fmaxf(t0, t1);
    float w0 = __builtin_amdgcn_exp2f(t0 - T);
    float w1 = __builtin_amdgcn_exp2f(t1 - T);
    float inv = 1.0f/(w0 + w1);
    w0 *= inv; w1 *= inv;

    const f16* p0 = oP + r0*64 + dh;
    const f16* p1 = oP + zr*64 + r0*64 + dh;
    float* op = out + ((size_t)b_*Lq + row)*Dq + h*HDq + dh;
    #pragma unroll
    for (int j=0;j<4;++j) {
        f16x8 a = *reinterpret_cast<const f16x8*>(p0 + j*8);
        f16x8 b = *reinterpret_cast<const f16x8*>(p1 + j*8);
        float4 v0, v1;
        v0.x = (float)a[0]*w0 + (float)b[0]*w1;
        v0.y = (float)a[1]*w0 + (float)b[1]*w1;
        v0.z = (float)a[2]*w0 + (float)b[2]*w1;
        v0.w = (float)a[3]*w0 + (float)b[3]*w1;
        v1.x = (float)a[4]*w0 + (float)b[4]*w1;
        v1.y = (float)a[5]*w0 + (float)b[5]*w1;
        v1.z = (float)a[6]*w0 + (float)b[6]*w1;
        v1.w = (float)a[7]*w0 + (float)b[7]*w1;
        *reinterpret_cast<float4*>(op + j*8)     = v0;
        *reinterpret_cast<float4*>(op + j*8 + 4) = v1;
    }
}

extern "C" void kernel_launch(void* const* d_in, const int* in_sizes, int n_in,
                              void* d_out, int out_size, void* d_ws, size_t ws_size,
                              hipStream_t stream) {
    const float* x       = (const float*)d_in[0];
    const float* quantum = (const float*)d_in[1];
    const float* wq      = (const float*)d_in[2];
    const float* wk      = (const float*)d_in[3];
    const float* wv      = (const float*)d_in[4];
    const float* scale   = (const float*)d_in[5];
    float* out = (float*)d_out;

    f16* ws     = (f16*)d_ws;
    f16* x_h    = ws;
    f16* wq_h   = ws + 4194304;
    f16* wk_h   = ws + 5242880;
    f16* wv_h   = ws + 6291456;
    f16* q_h    = ws + 7340032;
    f16* k_h    = ws + 11534336;
    f16* vT_h   = ws + 15728640;
    float* qm32 = (float*)(ws + 19922944);   // 8,388,608 f32
    f16* oP     = ws + 36700160;             // 8,388,608 f16 (2 z-halves)
    float* tP   = (float*)(ws + 45088768);   // 131,072 f32

    convert_kernel<<<1024, 256, 0, stream>>>(x, wq, wk, wv, x_h, wq_h, wk_h, wv_h);

    dim3 gq(64, 32, 2);
    qm_pre_kernel<<<gq, 256, 0, stream>>>(quantum, qm32);

    dim3 g1(Dq/GBN, (Bq*Lq)/GBM, 3);
    qkv_mfma_kernel<<<g1, 256, 0, stream>>>(x_h, wq_h, wk_h, wv_h, q_h, k_h, vT_h);

    dim3 g2(Bq*Hq, Lq/128, 2);
    attn4_kernel<<<g2, 256, 0, stream>>>(q_h, k_h, vT_h, qm32, scale, oP, tP);

    dim3 g3(Bq*Hq, Lq/128);
    combine_kernel<<<g3, 256, 0, stream>>>(oP, tP, out);
}

// Round 13
// 130.638 us; speedup vs baseline: 3.1636x; 1.5120x over previous
//
#include <hip/hip_runtime.h>

#define Bq 2
#define Lq 2048
#define Dq 1024
#define Hq 16
#define HDq 64

typedef _Float16 f16;
typedef _Float16 f16x8 __attribute__((ext_vector_type(8)));
typedef _Float16 f16x4 __attribute__((ext_vector_type(4)));
typedef __fp16 hf16x2 __attribute__((ext_vector_type(2)));
typedef float f32x4 __attribute__((ext_vector_type(4)));
typedef float f32x16 __attribute__((ext_vector_type(16)));

__device__ __forceinline__ void gload_lds16(const void* g, void* l) {
    __builtin_amdgcn_global_load_lds(
        (const __attribute__((address_space(1))) unsigned int*)g,
        (__attribute__((address_space(3))) unsigned int*)l, 16, 0, 0);
}

__device__ __forceinline__ void swap32(int& a, int& b) {
    asm volatile("v_permlane32_swap_b32 %0, %1" : "+v"(a), "+v"(b));
}

__device__ __forceinline__ int pk2(float a, float b) {
    hf16x2 v = __builtin_amdgcn_cvt_pkrtz(a, b);
    return __builtin_bit_cast(int, v);
}

// ---------------- fp32 -> fp16 conversion ------------------------------------
__global__ __launch_bounds__(256) void convert_kernel(
    const float* __restrict__ x,
    const float* __restrict__ wq, const float* __restrict__ wk, const float* __restrict__ wv,
    f16* __restrict__ x_h, f16* __restrict__ wq_h, f16* __restrict__ wk_h, f16* __restrict__ wv_h)
{
    const int NX = Bq*Lq*Dq;
    const int NW = Dq*Dq;
    const int total4 = (NX + 3*NW) / 4;
    for (int i = blockIdx.x*blockDim.x + threadIdx.x; i < total4;
         i += gridDim.x*blockDim.x) {
        int e = i * 4;
        const float* src; f16* dst; int off;
        if (e < NX) { src = x; dst = x_h; off = e; }
        else {
            int t = e - NX; int w = t >> 20; off = t & (NW-1);
            src = (w==0) ? wq : (w==1) ? wk : wv;
            dst = (w==0) ? wq_h : (w==1) ? wk_h : wv_h;
        }
        float4 v = *reinterpret_cast<const float4*>(src + off);
        f16x4 hv; hv.x=(f16)v.x; hv.y=(f16)v.y; hv.z=(f16)v.z; hv.w=(f16)v.w;
        *reinterpret_cast<f16x4*>(dst + off) = hv;
    }
}

// ---------------- QKV projection, fp16 MFMA ----------------------------------
#define GBM 128
#define GBN 128
#define GBK 32

__global__ __launch_bounds__(256) void qkv_mfma_kernel(
    const f16* __restrict__ x_h,
    const f16* __restrict__ wq_h, const f16* __restrict__ wk_h, const f16* __restrict__ wv_h,
    f16* __restrict__ q_h, f16* __restrict__ k_h, f16* __restrict__ vT_h)
{
    __shared__ __align__(16) f16 As[GBM*GBK];
    __shared__ __align__(16) f16 Bs[GBN*GBK];

    const int tid  = threadIdx.x;
    const int lane = tid & 63;
    const int wave = tid >> 6;
    const int wr = wave >> 1, wc = wave & 1;
    const int l15 = lane & 15, l4 = lane >> 4;
    const int n0 = blockIdx.x * GBN;
    const int m0 = blockIdx.y * GBM;
    const int z  = blockIdx.z;
    const f16* W = (z==0) ? wq_h : (z==1) ? wk_h : wv_h;

    const int sslot = tid & 3;

    f32x4 acc[4][4];
    #pragma unroll
    for (int i=0;i<4;++i)
        #pragma unroll
        for (int j=0;j<4;++j) acc[i][j] = f32x4{0.f,0.f,0.f,0.f};

    for (int kt = 0; kt < Dq; kt += GBK) {
        __syncthreads();
        #pragma unroll
        for (int j = 0; j < 2; ++j) {
            int slotIdx = tid + j*256;
            int row = slotIdx >> 2;
            gload_lds16(x_h + (size_t)(m0+row)*Dq + kt + sslot*8,
                        (char*)As + slotIdx*16);
            gload_lds16(W   + (size_t)(n0+row)*Dq + kt + sslot*8,
                        (char*)Bs + slotIdx*16);
        }
        __syncthreads();

        f16x8 a[4], b[4];
        #pragma unroll
        for (int m=0;m<4;++m) {
            int row = wr*64 + m*16 + l15;
            a[m] = *reinterpret_cast<const f16x8*>((const char*)As + row*64 + l4*16);
        }
        #pragma unroll
        for (int n=0;n<4;++n) {
            int row = wc*64 + n*16 + l15;
            b[n] = *reinterpret_cast<const f16x8*>((const char*)Bs + row*64 + l4*16);
        }
        #pragma unroll
        for (int m=0;m<4;++m)
            #pragma unroll
            for (int n=0;n<4;++n)
                acc[m][n] = __builtin_amdgcn_mfma_f32_16x16x32_f16(a[m], b[n], acc[m][n], 0,0,0);
    }

    #pragma unroll
    for (int m=0;m<4;++m) {
        #pragma unroll
        for (int r=0;r<4;++r) {
            int grow = m0 + wr*64 + m*16 + l4*4 + r;
            int b_   = grow >> 11;
            int lrow = grow & (Lq-1);
            #pragma unroll
            for (int n=0;n<4;++n) {
                int gcol = n0 + wc*64 + n*16 + l15;
                int h = gcol >> 6, d = gcol & 63;
                int bh = b_*Hq + h;
                f16 val = (f16)acc[m][n][r];
                if (z==0)      q_h[((size_t)bh*Lq + lrow)*HDq + d] = val;
                else if (z==1) k_h[((size_t)bh*Lq + lrow)*HDq + d] = val;
                else           vT_h[((size_t)bh*HDq + d)*Lq + lrow] = val;
            }
        }
    }
}

// ---------------- quantum -> fragment-ordered fp16 tiles ---------------------
__global__ __launch_bounds__(256) void qm_pre_kernel(
    const float* __restrict__ quantum, f16* __restrict__ qm_pre)
{
    __shared__ float qs[32][64];
    const int tid = threadIdx.x;
    const int qt = blockIdx.x, kt = blockIdx.y, b = blockIdx.z;
    const float* base = quantum + ((size_t)b*Lq + qt*32)*Lq + kt*64;
    #pragma unroll
    for (int i=0;i<2;++i) {
        int idx = tid + i*256;
        int r = idx >> 4, c = (idx & 15)*4;
        float4 v = *reinterpret_cast<const float4*>(base + (size_t)r*Lq + c);
        qs[r][c]=v.x; qs[r][c+1]=v.y; qs[r][c+2]=v.z; qs[r][c+3]=v.w;
    }
    __syncthreads();
    const int seg = tid >> 6, lane = tid & 63, l31 = lane & 31, hi = lane >> 5;
    f16x8 u;
    #pragma unroll
    for (int e=0;e<8;++e) {
        int key = 16*seg + 8*(e>>2) + 4*hi + (e&3);
        u[e] = (f16)qs[l31][key];
    }
    f16* outp = qm_pre + (((size_t)b*32 + kt)*64 + qt)*2048 + seg*512 + lane*8;
    *reinterpret_cast<f16x8*>(outp) = u;
}

// ---------------- flash attention: 4 waves x 32 q-rows, triple-buffered ------
// single barrier per iter, counted vmcnt, qm register prefetch (ping-pong)
__global__ __launch_bounds__(256, 2) void attn4_kernel(
    const f16* __restrict__ q_h, const f16* __restrict__ k_h, const f16* __restrict__ vT_h,
    const f16* __restrict__ qm_pre, const float* __restrict__ scale,
    float* __restrict__ out)
{
    __shared__ __align__(16) char lds[49152];   // 3 bufs x [K 8KB | V 8KB]

    const int tid  = threadIdx.x;
    const int lane = tid & 63;
    const int wave = tid >> 6;          // 0..3
    const int l31  = lane & 31;
    const int hi   = lane >> 5;
    const int bh = blockIdx.x;
    const int qb = blockIdx.y;
    const int b_ = bh >> 4, h = bh & 15;
    const int qW = qb*128 + wave*32;    // this wave's 32 q-rows
    const int qt = qb*4 + wave;         // 32-row quantum tile index
    const float sc = scale[h];
    const float c1 = 0.125f * sc * 1.44269504f;
    const float c2 = sc * 1.44269504f;

    const f16* kbase = k_h  + (size_t)bh*Lq*HDq;
    const f16* vbase = vT_h + (size_t)bh*HDq*Lq;

    // Q fragments (B-operand: qrow=l31, d = ds*16+hi*8+e)
    f16x8 qf[4];
    {
        const f16* qb_ = q_h + ((size_t)bh*Lq + qW + l31)*HDq + hi*8;
        #pragma unroll
        for (int ds=0; ds<4; ++ds)
            qf[ds] = *reinterpret_cast<const f16x8*>(qb_ + ds*16);
    }

    f32x16 o0, o1;
    #pragma unroll
    for (int r=0;r<16;++r) { o0[r]=0.f; o1[r]=0.f; }
    float m_run = -1e30f, s_run = 0.f;

    auto STAGE = [&](int t, int buf) {
        const int k0 = t*64;
        char* LK = lds + buf*16384;
        char* LV = LK + 8192;
        #pragma unroll
        for (int i=0;i<2;++i) {
            int g = tid + i*256;                 // 0..511
            int row = g >> 3, slot = g & 7;
            int ss = slot ^ (row & 7);
            gload_lds16(kbase + (size_t)(k0+row)*HDq + ss*8, LK + g*16);
            gload_lds16(vbase + (size_t)row*Lq + k0 + ss*8,  LV + g*16);
        }
    };

    auto QMLOAD = [&](int t, f16x8 (&qm)[4]) {
        const f16* qmb = qm_pre + (((size_t)b_*32 + t)*64 + qt)*2048 + lane*8;
        #pragma unroll
        for (int s=0;s<4;++s)
            qm[s] = *reinterpret_cast<const f16x8*>(qmb + s*512);
    };

    auto COMPUTE = [&](int t, int buf, f16x8 (&qmc)[4], f16x8 (&qmn)[4]) {
        const char* LK = lds + buf*16384;
        const char* LV = LK + 8192;
        // prefetch next iteration's quantum fragments (consumed next iter)
        int tn = (t+1 < 32) ? t+1 : 31;
        QMLOAD(tn, qmn);

        // S^T = K Q^T (two 32-key tiles)
        f32x16 st[2];
        __builtin_amdgcn_s_setprio(1);
        #pragma unroll
        for (int kt=0;kt<2;++kt) {
            #pragma unroll
            for (int r=0;r<16;++r) st[kt][r]=0.f;
            #pragma unroll
            for (int ds=0;ds<4;++ds) {
                f16x8 ka = *reinterpret_cast<const f16x8*>(
                    LK + ((kt*32+l31)<<7) + (((ds*2+hi)^(l31&7))<<4));
                st[kt] = __builtin_amdgcn_mfma_f32_32x32x16_f16(ka, qf[ds], st[kt], 0,0,0);
            }
        }
        __builtin_amdgcn_s_setprio(0);

        // logits (base-2)
        float lg[32];
        #pragma unroll
        for (int s=0;s<4;++s)
            #pragma unroll
            for (int e=0;e<8;++e) {
                int i = s*8 + e;
                float sv = (i < 16) ? st[0][i] : st[1][i-16];
                lg[i] = sv*c1 + (float)qmc[s][e]*c2;
            }

        // tile max: pairwise tree
        float tm[16];
        #pragma unroll
        for (int r=0;r<16;++r) tm[r] = fmaxf(lg[r], lg[r+16]);
        #pragma unroll
        for (int w=8; w>0; w>>=1)
            #pragma unroll
            for (int r=0;r<w;++r) tm[r] = fmaxf(tm[r], tm[r+w]);
        float tmax = fmaxf(tm[0], __shfl_xor(tm[0], 32));

        if (!__all(tmax <= m_run + 8.f)) {
            float m_new = fmaxf(m_run, tmax);
            float corr = __builtin_amdgcn_exp2f(m_run - m_new);
            m_run = m_new;
            s_run *= corr;
            #pragma unroll
            for (int r=0;r<16;++r) { o0[r] *= corr; o1[r] *= corr; }
        }

        // P = 2^(lg - m); sum via tree
        float p[32];
        #pragma unroll
        for (int r=0;r<32;++r) p[r] = __builtin_amdgcn_exp2f(lg[r] - m_run);
        float sm[16];
        #pragma unroll
        for (int r=0;r<16;++r) sm[r] = p[r] + p[r+16];
        #pragma unroll
        for (int w=8; w>0; w>>=1)
            #pragma unroll
            for (int r=0;r<w;++r) sm[r] += sm[r+w];
        s_run += sm[0];

        // pack P -> B-operand fragments
        f16x8 pb[4];
        #pragma unroll
        for (int ks=0; ks<4; ++ks) {
            int w0 = pk2(p[8*ks+0], p[8*ks+1]);
            int w1 = pk2(p[8*ks+2], p[8*ks+3]);
            int w2 = pk2(p[8*ks+4], p[8*ks+5]);
            int w3 = pk2(p[8*ks+6], p[8*ks+7]);
            swap32(w0, w2);
            swap32(w1, w3);
            union { int w[4]; f16x8 v; } u;
            u.w[0]=w0; u.w[1]=w1; u.w[2]=w2; u.w[3]=w3;
            pb[ks] = u.v;
        }

        // O^T += V^T P^T
        __builtin_amdgcn_s_setprio(1);
        #pragma unroll
        for (int ks=0; ks<4; ++ks) {
            f16x8 va0 = *reinterpret_cast<const f16x8*>(
                LV + (l31<<7)        + (((ks*2+hi)^(l31&7))<<4));
            f16x8 va1 = *reinterpret_cast<const f16x8*>(
                LV + ((32+l31)<<7)   + (((ks*2+hi)^(l31&7))<<4));
            o0 = __builtin_amdgcn_mfma_f32_32x32x16_f16(va0, pb[ks], o0, 0,0,0);
            o1 = __builtin_amdgcn_mfma_f32_32x32x16_f16(va1, pb[ks], o1, 0,0,0);
        }
        __builtin_amdgcn_s_setprio(0);
    };

    f16x8 qmE[4], qmO[4];

    // prologue: qm for t=0, then K/V tiles 0,1
    QMLOAD(0, qmE);
    STAGE(0, 0);
    STAGE(1, 1);

    #define VMW(n) asm volatile("s_waitcnt vmcnt(" #n ")" ::: "memory")

    // t = 0  (younger than STAGE(0): STAGE(1)=4)
    VMW(4);  __builtin_amdgcn_s_barrier();
    STAGE(2, 2);  COMPUTE(0, 0, qmE, qmO);
    // t = 1  (younger than STAGE(1): STAGE(2)+Qp(0)=8)
    VMW(8);  __builtin_amdgcn_s_barrier();
    STAGE(3, 0);  COMPUTE(1, 1, qmO, qmE);
    // t = 2..29 (steady: younger than STAGE(t): Qp+STAGE+Qp = 12)
    for (int t = 2; t < 30; t += 2) {
        VMW(12); __builtin_amdgcn_s_barrier();
        STAGE(t+2, (t+2)%3); COMPUTE(t, t%3, qmE, qmO);
        VMW(12); __builtin_amdgcn_s_barrier();
        STAGE(t+3, (t+3)%3); COMPUTE(t+1, (t+1)%3, qmO, qmE);
    }
    // t = 30 (younger than STAGE(30): Qp(28)+STAGE(31)+Qp(29)=12)
    VMW(12); __builtin_amdgcn_s_barrier();
    COMPUTE(30, 0, qmE, qmO);
    // t = 31 (younger than STAGE(31): Qp(29)+Qp(30)=8)
    VMW(8);  __builtin_amdgcn_s_barrier();
    COMPUTE(31, 1, qmO, qmE);

    #undef VMW

    // epilogue
    float s_tot = s_run + __shfl_xor(s_run, 32);
    float inv = 1.0f / s_tot;
    float* ob = out + ((size_t)b_*Lq + qW + l31)*Dq + h*HDq;
    #pragma unroll
    for (int r=0;r<16;++r) {
        int drow = (r&3) + 8*(r>>2) + 4*hi;
        ob[drow]      = o0[r]*inv;
        ob[32 + drow] = o1[r]*inv;
    }
}

extern "C" void kernel_launch(void* const* d_in, const int* in_sizes, int n_in,
                              void* d_out, int out_size, void* d_ws, size_t ws_size,
                              hipStream_t stream) {
    const float* x       = (const float*)d_in[0];
    const float* quantum = (const float*)d_in[1];
    const float* wq      = (const float*)d_in[2];
    const float* wk      = (const float*)d_in[3];
    const float* wv      = (const float*)d_in[4];
    const float* scale   = (const float*)d_in[5];
    float* out = (float*)d_out;

    f16* ws     = (f16*)d_ws;
    f16* x_h    = ws;
    f16* wq_h   = ws + 4194304;
    f16* wk_h   = ws + 5242880;
    f16* wv_h   = ws + 6291456;
    f16* q_h    = ws + 7340032;
    f16* k_h    = ws + 11534336;
    f16* vT_h   = ws + 15728640;
    f16* qm_pre = ws + 19922944;

    convert_kernel<<<1024, 256, 0, stream>>>(x, wq, wk, wv, x_h, wq_h, wk_h, wv_h);

    dim3 gq(64, 32, 2);
    qm_pre_kernel<<<gq, 256, 0, stream>>>(quantum, qm_pre);

    dim3 g1(Dq/GBN, (Bq*Lq)/GBM, 3);
    qkv_mfma_kernel<<<g1, 256, 0, stream>>>(x_h, wq_h, wk_h, wv_h, q_h, k_h, vT_h);

    // all q-blocks of one bh land on one XCD (linear id % 8 = bh % 8)
    dim3 g2(Bq*Hq, Lq/128);
    attn4_kernel<<<g2, 256, 0, stream>>>(q_h, k_h, vT_h, qm_pre, scale, out);
}

// Round 14
// 127.115 us; speedup vs baseline: 3.2513x; 1.0277x over previous
//
#include <hip/hip_runtime.h>

#define Bq 2
#define Lq 2048
#define Dq 1024
#define Hq 16
#define HDq 64

typedef _Float16 f16;
typedef _Float16 f16x8 __attribute__((ext_vector_type(8)));
typedef _Float16 f16x4 __attribute__((ext_vector_type(4)));
typedef __fp16 hf16x2 __attribute__((ext_vector_type(2)));
typedef float f32x4 __attribute__((ext_vector_type(4)));
typedef float f32x16 __attribute__((ext_vector_type(16)));

__device__ __forceinline__ void gload_lds16(const void* g, void* l) {
    __builtin_amdgcn_global_load_lds(
        (const __attribute__((address_space(1))) unsigned int*)g,
        (__attribute__((address_space(3))) unsigned int*)l, 16, 0, 0);
}

__device__ __forceinline__ void swap32(int& a, int& b) {
    asm volatile("v_permlane32_swap_b32 %0, %1" : "+v"(a), "+v"(b));
}

__device__ __forceinline__ int pk2(float a, float b) {
    hf16x2 v = __builtin_amdgcn_cvt_pkrtz(a, b);
    return __builtin_bit_cast(int, v);
}

// ---------------- fp32 -> fp16 conversion ------------------------------------
__global__ __launch_bounds__(256) void convert_kernel(
    const float* __restrict__ x,
    const float* __restrict__ wq, const float* __restrict__ wk, const float* __restrict__ wv,
    f16* __restrict__ x_h, f16* __restrict__ wq_h, f16* __restrict__ wk_h, f16* __restrict__ wv_h)
{
    const int NX = Bq*Lq*Dq;
    const int NW = Dq*Dq;
    const int total4 = (NX + 3*NW) / 4;
    for (int i = blockIdx.x*blockDim.x + threadIdx.x; i < total4;
         i += gridDim.x*blockDim.x) {
        int e = i * 4;
        const float* src; f16* dst; int off;
        if (e < NX) { src = x; dst = x_h; off = e; }
        else {
            int t = e - NX; int w = t >> 20; off = t & (NW-1);
            src = (w==0) ? wq : (w==1) ? wk : wv;
            dst = (w==0) ? wq_h : (w==1) ? wk_h : wv_h;
        }
        float4 v = *reinterpret_cast<const float4*>(src + off);
        f16x4 hv; hv.x=(f16)v.x; hv.y=(f16)v.y; hv.z=(f16)v.z; hv.w=(f16)v.w;
        *reinterpret_cast<f16x4*>(dst + off) = hv;
    }
}

// ------- fused: QKV projection (id<768) + quantum transpose (id>=768) --------
#define GBM 128
#define GBN 128
#define GBK 32

__global__ __launch_bounds__(256) void qkv_qm_fused_kernel(
    const f16* __restrict__ x_h,
    const f16* __restrict__ wq_h, const f16* __restrict__ wk_h, const f16* __restrict__ wv_h,
    const float* __restrict__ quantum,
    f16* __restrict__ q_h, f16* __restrict__ k_h, f16* __restrict__ vT_h,
    f16* __restrict__ qm_pre)
{
    __shared__ __align__(16) char smem[16384];
    const int tid = threadIdx.x;
    const int id  = blockIdx.x;

    if (id < 768) {
        // ---------------- GEMM block ----------------
        f16* As = (f16*)smem;             // [GBM*GBK] = 8KB
        f16* Bs = (f16*)(smem + 8192);    // [GBN*GBK] = 8KB
        const int lane = tid & 63;
        const int wave = tid >> 6;
        const int wr = wave >> 1, wc = wave & 1;
        const int l15 = lane & 15, l4 = lane >> 4;
        const int n0 = (id & 7) * GBN;
        const int m0 = ((id >> 3) & 31) * GBM;
        const int z  = id >> 8;
        const f16* W = (z==0) ? wq_h : (z==1) ? wk_h : wv_h;
        const int sslot = tid & 3;

        f32x4 acc[4][4];
        #pragma unroll
        for (int i=0;i<4;++i)
            #pragma unroll
            for (int j=0;j<4;++j) acc[i][j] = f32x4{0.f,0.f,0.f,0.f};

        for (int kt = 0; kt < Dq; kt += GBK) {
            __syncthreads();
            #pragma unroll
            for (int j = 0; j < 2; ++j) {
                int slotIdx = tid + j*256;
                int row = slotIdx >> 2;
                gload_lds16(x_h + (size_t)(m0+row)*Dq + kt + sslot*8,
                            (char*)As + slotIdx*16);
                gload_lds16(W   + (size_t)(n0+row)*Dq + kt + sslot*8,
                            (char*)Bs + slotIdx*16);
            }
            __syncthreads();

            f16x8 a[4], b[4];
            #pragma unroll
            for (int m=0;m<4;++m) {
                int row = wr*64 + m*16 + l15;
                a[m] = *reinterpret_cast<const f16x8*>((const char*)As + row*64 + l4*16);
            }
            #pragma unroll
            for (int n=0;n<4;++n) {
                int row = wc*64 + n*16 + l15;
                b[n] = *reinterpret_cast<const f16x8*>((const char*)Bs + row*64 + l4*16);
            }
            #pragma unroll
            for (int m=0;m<4;++m)
                #pragma unroll
                for (int n=0;n<4;++n)
                    acc[m][n] = __builtin_amdgcn_mfma_f32_16x16x32_f16(a[m], b[n], acc[m][n], 0,0,0);
        }

        #pragma unroll
        for (int m=0;m<4;++m) {
            #pragma unroll
            for (int r=0;r<4;++r) {
                int grow = m0 + wr*64 + m*16 + l4*4 + r;
                int b_   = grow >> 11;
                int lrow = grow & (Lq-1);
                #pragma unroll
                for (int n=0;n<4;++n) {
                    int gcol = n0 + wc*64 + n*16 + l15;
                    int h = gcol >> 6, d = gcol & 63;
                    int bh = b_*Hq + h;
                    f16 val = (f16)acc[m][n][r];
                    if (z==0)      q_h[((size_t)bh*Lq + lrow)*HDq + d] = val;
                    else if (z==1) k_h[((size_t)bh*Lq + lrow)*HDq + d] = val;
                    else           vT_h[((size_t)bh*HDq + d)*Lq + lrow] = val;
                }
            }
        }
    } else {
        // ---------------- quantum transpose block ----------------
        float (*qs)[64] = (float(*)[64])smem;   // 8KB
        const int q  = id - 768;
        const int qt = q & 63;
        const int kt = (q >> 6) & 31;
        const int b  = q >> 11;
        const float* base = quantum + ((size_t)b*Lq + qt*32)*Lq + kt*64;
        #pragma unroll
        for (int i=0;i<2;++i) {
            int idx = tid + i*256;
            int r = idx >> 4, c = (idx & 15)*4;
            float4 v = *reinterpret_cast<const float4*>(base + (size_t)r*Lq + c);
            qs[r][c]=v.x; qs[r][c+1]=v.y; qs[r][c+2]=v.z; qs[r][c+3]=v.w;
        }
        __syncthreads();
        const int seg = tid >> 6, lane = tid & 63, l31 = lane & 31, hi = lane >> 5;
        f16x8 u;
        #pragma unroll
        for (int e=0;e<8;++e) {
            int key = 16*seg + 8*(e>>2) + 4*hi + (e&3);
            u[e] = (f16)qs[l31][key];
        }
        f16* outp = qm_pre + (((size_t)b*32 + kt)*64 + qt)*2048 + seg*512 + lane*8;
        *reinterpret_cast<f16x8*>(outp) = u;
    }
}

// ---- flash attention: 4 waves x 32 q-rows, 128-key epochs, 64KB dbuf --------
__global__ __launch_bounds__(256, 2) void attn4_kernel(
    const f16* __restrict__ q_h, const f16* __restrict__ k_h, const f16* __restrict__ vT_h,
    const f16* __restrict__ qm_pre, const float* __restrict__ scale,
    float* __restrict__ out)
{
    __shared__ __align__(16) char lds[65536];   // 4 quarters x [K 8KB | V 8KB]

    const int tid  = threadIdx.x;
    const int lane = tid & 63;
    const int wave = tid >> 6;          // 0..3
    const int l31  = lane & 31;
    const int hi   = lane >> 5;
    const int bh = blockIdx.x;
    const int qb = blockIdx.y;
    const int b_ = bh >> 4, h = bh & 15;
    const int qW = qb*128 + wave*32;    // this wave's 32 q-rows
    const int qt = qb*4 + wave;         // 32-row quantum tile index
    const float sc = scale[h];
    const float c1 = 0.125f * sc * 1.44269504f;
    const float c2 = sc * 1.44269504f;

    const f16* kbase = k_h  + (size_t)bh*Lq*HDq;
    const f16* vbase = vT_h + (size_t)bh*HDq*Lq;

    // Q fragments (B-operand: qrow=l31, d = ds*16+hi*8+e)
    f16x8 qf[4];
    {
        const f16* qb_ = q_h + ((size_t)bh*Lq + qW + l31)*HDq + hi*8;
        #pragma unroll
        for (int ds=0; ds<4; ++ds)
            qf[ds] = *reinterpret_cast<const f16x8*>(qb_ + ds*16);
    }

    f32x16 o0, o1;
    #pragma unroll
    for (int r=0;r<16;++r) { o0[r]=0.f; o1[r]=0.f; }
    float m_run = -1e30f, s_run = 0.f;

    // tile t (0..31) lives in quarter ((t>>1)&1)*2 + (t&1)
    auto QTR = [](int t) { return ((t >> 1) & 1)*2 + (t & 1); };

    auto STAGE = [&](int t) {
        const int k0 = t*64;
        char* LK = lds + QTR(t)*16384;
        char* LV = LK + 8192;
        #pragma unroll
        for (int i=0;i<2;++i) {
            int g = tid + i*256;                 // 0..511
            int row = g >> 3, slot = g & 7;
            int ss = slot ^ (row & 7);
            gload_lds16(kbase + (size_t)(k0+row)*HDq + ss*8, LK + g*16);
            gload_lds16(vbase + (size_t)row*Lq + k0 + ss*8,  LV + g*16);
        }
    };

    auto QMLOAD = [&](int t, f16x8 (&qm)[4]) {
        const f16* qmb = qm_pre + (((size_t)b_*32 + t)*64 + qt)*2048 + lane*8;
        #pragma unroll
        for (int s=0;s<4;++s)
            qm[s] = *reinterpret_cast<const f16x8*>(qmb + s*512);
    };

    auto COMPUTE = [&](int t, f16x8 (&qmc)[4], f16x8 (&qmn)[4]) {
        const char* LK = lds + QTR(t)*16384;
        const char* LV = LK + 8192;
        // prefetch next tile's quantum fragments (consumed next COMPUTE)
        int tn = (t+1 < 32) ? t+1 : 31;
        QMLOAD(tn, qmn);

        // S^T = K Q^T (two 32-key tiles)
        f32x16 st[2];
        __builtin_amdgcn_s_setprio(1);
        #pragma unroll
        for (int kt=0;kt<2;++kt) {
            #pragma unroll
            for (int r=0;r<16;++r) st[kt][r]=0.f;
            #pragma unroll
            for (int ds=0;ds<4;++ds) {
                f16x8 ka = *reinterpret_cast<const f16x8*>(
                    LK + ((kt*32+l31)<<7) + (((ds*2+hi)^(l31&7))<<4));
                st[kt] = __builtin_amdgcn_mfma_f32_32x32x16_f16(ka, qf[ds], st[kt], 0,0,0);
            }
        }
        __builtin_amdgcn_s_setprio(0);

        // logits (base-2)
        float lg[32];
        #pragma unroll
        for (int s=0;s<4;++s)
            #pragma unroll
            for (int e=0;e<8;++e) {
                int i = s*8 + e;
                float sv = (i < 16) ? st[0][i] : st[1][i-16];
                lg[i] = sv*c1 + (float)qmc[s][e]*c2;
            }

        // tile max: pairwise tree
        float tm[16];
        #pragma unroll
        for (int r=0;r<16;++r) tm[r] = fmaxf(lg[r], lg[r+16]);
        #pragma unroll
        for (int w=8; w>0; w>>=1)
            #pragma unroll
            for (int r=0;r<w;++r) tm[r] = fmaxf(tm[r], tm[r+w]);
        float tmax = fmaxf(tm[0], __shfl_xor(tm[0], 32));

        if (!__all(tmax <= m_run + 8.f)) {
            float m_new = fmaxf(m_run, tmax);
            float corr = __builtin_amdgcn_exp2f(m_run - m_new);
            m_run = m_new;
            s_run *= corr;
            #pragma unroll
            for (int r=0;r<16;++r) { o0[r] *= corr; o1[r] *= corr; }
        }

        // P = 2^(lg - m); sum via tree
        float p[32];
        #pragma unroll
        for (int r=0;r<32;++r) p[r] = __builtin_amdgcn_exp2f(lg[r] - m_run);
        float sm[16];
        #pragma unroll
        for (int r=0;r<16;++r) sm[r] = p[r] + p[r+16];
        #pragma unroll
        for (int w=8; w>0; w>>=1)
            #pragma unroll
            for (int r=0;r<w;++r) sm[r] += sm[r+w];
        s_run += sm[0];

        // pack P -> B-operand fragments
        f16x8 pb[4];
        #pragma unroll
        for (int ks=0; ks<4; ++ks) {
            int w0 = pk2(p[8*ks+0], p[8*ks+1]);
            int w1 = pk2(p[8*ks+2], p[8*ks+3]);
            int w2 = pk2(p[8*ks+4], p[8*ks+5]);
            int w3 = pk2(p[8*ks+6], p[8*ks+7]);
            swap32(w0, w2);
            swap32(w1, w3);
            union { int w[4]; f16x8 v; } u;
            u.w[0]=w0; u.w[1]=w1; u.w[2]=w2; u.w[3]=w3;
            pb[ks] = u.v;
        }

        // O^T += V^T P^T
        __builtin_amdgcn_s_setprio(1);
        #pragma unroll
        for (int ks=0; ks<4; ++ks) {
            f16x8 va0 = *reinterpret_cast<const f16x8*>(
                LV + (l31<<7)        + (((ks*2+hi)^(l31&7))<<4));
            f16x8 va1 = *reinterpret_cast<const f16x8*>(
                LV + ((32+l31)<<7)   + (((ks*2+hi)^(l31&7))<<4));
            o0 = __builtin_amdgcn_mfma_f32_32x32x16_f16(va0, pb[ks], o0, 0,0,0);
            o1 = __builtin_amdgcn_mfma_f32_32x32x16_f16(va1, pb[ks], o1, 0,0,0);
        }
        __builtin_amdgcn_s_setprio(0);
    };

    f16x8 qmE[4], qmO[4];

    // prologue: qm(0) + epoch-0 tiles (0,1 -> quarters 0,1)
    QMLOAD(0, qmE);
    STAGE(0); STAGE(1);

    #define VMW(n) asm volatile("s_waitcnt vmcnt(" #n ")" ::: "memory")

    // one barrier per 128-key epoch; 2 buffers of 2 sub-tiles.
    // At epoch-e barrier all waves finished epoch e-1's COMPUTEs of
    // buf (e+1)&1, so STAGE(2e+2),(2e+3) may overwrite it.
    // vmcnt: younger than epoch-e's stages = 2 QM prefetches = 8 (epoch 0: 0).
    VMW(0); __builtin_amdgcn_s_barrier();
    STAGE(2); STAGE(3);
    COMPUTE(0, qmE, qmO);
    COMPUTE(1, qmO, qmE);
    for (int e = 1; e < 15; ++e) {
        VMW(8); __builtin_amdgcn_s_barrier();
        STAGE(2*e+2); STAGE(2*e+3);
        COMPUTE(2*e,   qmE, qmO);
        COMPUTE(2*e+1, qmO, qmE);
    }
    // epoch 15: no further stage
    VMW(8); __builtin_amdgcn_s_barrier();
    COMPUTE(30, qmE, qmO);
    COMPUTE(31, qmO, qmE);

    #undef VMW

    // epilogue
    float s_tot = s_run + __shfl_xor(s_run, 32);
    float inv = 1.0f / s_tot;
    float* ob = out + ((size_t)b_*Lq + qW + l31)*Dq + h*HDq;
    #pragma unroll
    for (int r=0;r<16;++r) {
        int drow = (r&3) + 8*(r>>2) + 4*hi;
        ob[drow]      = o0[r]*inv;
        ob[32 + drow] = o1[r]*inv;
    }
}

extern "C" void kernel_launch(void* const* d_in, const int* in_sizes, int n_in,
                              void* d_out, int out_size, void* d_ws, size_t ws_size,
                              hipStream_t stream) {
    const float* x       = (const float*)d_in[0];
    const float* quantum = (const float*)d_in[1];
    const float* wq      = (const float*)d_in[2];
    const float* wk      = (const float*)d_in[3];
    const float* wv      = (const float*)d_in[4];
    const float* scale   = (const float*)d_in[5];
    float* out = (float*)d_out;

    f16* ws     = (f16*)d_ws;
    f16* x_h    = ws;
    f16* wq_h   = ws + 4194304;
    f16* wk_h   = ws + 5242880;
    f16* wv_h   = ws + 6291456;
    f16* q_h    = ws + 7340032;
    f16* k_h    = ws + 11534336;
    f16* vT_h   = ws + 15728640;
    f16* qm_pre = ws + 19922944;

    convert_kernel<<<1024, 256, 0, stream>>>(x, wq, wk, wv, x_h, wq_h, wk_h, wv_h);

    // fused: 768 GEMM blocks + 4096 quantum-transpose blocks
    qkv_qm_fused_kernel<<<4864, 256, 0, stream>>>(
        x_h, wq_h, wk_h, wv_h, quantum, q_h, k_h, vT_h, qm_pre);

    // all q-blocks of one bh land on one XCD (linear id % 8 = bh % 8)
    dim3 g2(Bq*Hq, Lq/128);
    attn4_kernel<<<g2, 256, 0, stream>>>(q_h, k_h, vT_h, qm_pre, scale, out);
}

// Round 15
// 126.880 us; speedup vs baseline: 3.2573x; 1.0019x over previous
//
#include <hip/hip_runtime.h>

#define Bq 2
#define Lq 2048
#define Dq 1024
#define Hq 16
#define HDq 64

typedef _Float16 f16;
typedef _Float16 f16x8 __attribute__((ext_vector_type(8)));
typedef _Float16 f16x4 __attribute__((ext_vector_type(4)));
typedef __fp16 hf16x2 __attribute__((ext_vector_type(2)));
typedef float f32x4 __attribute__((ext_vector_type(4)));
typedef float f32x16 __attribute__((ext_vector_type(16)));

__device__ __forceinline__ void gload_lds16(const void* g, void* l) {
    __builtin_amdgcn_global_load_lds(
        (const __attribute__((address_space(1))) unsigned int*)g,
        (__attribute__((address_space(3))) unsigned int*)l, 16, 0, 0);
}

__device__ __forceinline__ void swap32(int& a, int& b) {
    asm volatile("v_permlane32_swap_b32 %0, %1" : "+v"(a), "+v"(b));
}

__device__ __forceinline__ int pk2(float a, float b) {
    hf16x2 v = __builtin_amdgcn_cvt_pkrtz(a, b);
    return __builtin_bit_cast(int, v);
}

// ---------------- fp32 -> fp16 conversion ------------------------------------
__global__ __launch_bounds__(256) void convert_kernel(
    const float* __restrict__ x,
    const float* __restrict__ wq, const float* __restrict__ wk, const float* __restrict__ wv,
    f16* __restrict__ x_h, f16* __restrict__ wq_h, f16* __restrict__ wk_h, f16* __restrict__ wv_h)
{
    const int NX = Bq*Lq*Dq;
    const int NW = Dq*Dq;
    const int total4 = (NX + 3*NW) / 4;
    for (int i = blockIdx.x*blockDim.x + threadIdx.x; i < total4;
         i += gridDim.x*blockDim.x) {
        int e = i * 4;
        const float* src; f16* dst; int off;
        if (e < NX) { src = x; dst = x_h; off = e; }
        else {
            int t = e - NX; int w = t >> 20; off = t & (NW-1);
            src = (w==0) ? wq : (w==1) ? wk : wv;
            dst = (w==0) ? wq_h : (w==1) ? wk_h : wv_h;
        }
        float4 v = *reinterpret_cast<const float4*>(src + off);
        f16x4 hv; hv.x=(f16)v.x; hv.y=(f16)v.y; hv.z=(f16)v.z; hv.w=(f16)v.w;
        *reinterpret_cast<f16x4*>(dst + off) = hv;
    }
}

// ------- fused: QKV projection (id<768) + quantum transpose (id>=768) --------
#define GBM 128
#define GBN 128
#define GBK 32

__global__ __launch_bounds__(256) void qkv_qm_fused_kernel(
    const f16* __restrict__ x_h,
    const f16* __restrict__ wq_h, const f16* __restrict__ wk_h, const f16* __restrict__ wv_h,
    const float* __restrict__ quantum,
    f16* __restrict__ q_h, f16* __restrict__ k_h, f16* __restrict__ vT_h,
    f16* __restrict__ qm_pre)
{
    __shared__ __align__(16) char smem[16384];
    const int tid = threadIdx.x;
    const int id  = blockIdx.x;

    if (id < 768) {
        // ---------------- GEMM block ----------------
        f16* As = (f16*)smem;
        f16* Bs = (f16*)(smem + 8192);
        const int lane = tid & 63;
        const int wave = tid >> 6;
        const int wr = wave >> 1, wc = wave & 1;
        const int l15 = lane & 15, l4 = lane >> 4;
        const int n0 = (id & 7) * GBN;
        const int m0 = ((id >> 3) & 31) * GBM;
        const int z  = id >> 8;
        const f16* W = (z==0) ? wq_h : (z==1) ? wk_h : wv_h;
        const int sslot = tid & 3;

        f32x4 acc[4][4];
        #pragma unroll
        for (int i=0;i<4;++i)
            #pragma unroll
            for (int j=0;j<4;++j) acc[i][j] = f32x4{0.f,0.f,0.f,0.f};

        for (int kt = 0; kt < Dq; kt += GBK) {
            __syncthreads();
            #pragma unroll
            for (int j = 0; j < 2; ++j) {
                int slotIdx = tid + j*256;
                int row = slotIdx >> 2;
                gload_lds16(x_h + (size_t)(m0+row)*Dq + kt + sslot*8,
                            (char*)As + slotIdx*16);
                gload_lds16(W   + (size_t)(n0+row)*Dq + kt + sslot*8,
                            (char*)Bs + slotIdx*16);
            }
            __syncthreads();

            f16x8 a[4], b[4];
            #pragma unroll
            for (int m=0;m<4;++m) {
                int row = wr*64 + m*16 + l15;
                a[m] = *reinterpret_cast<const f16x8*>((const char*)As + row*64 + l4*16);
            }
            #pragma unroll
            for (int n=0;n<4;++n) {
                int row = wc*64 + n*16 + l15;
                b[n] = *reinterpret_cast<const f16x8*>((const char*)Bs + row*64 + l4*16);
            }
            #pragma unroll
            for (int m=0;m<4;++m)
                #pragma unroll
                for (int n=0;n<4;++n)
                    acc[m][n] = __builtin_amdgcn_mfma_f32_16x16x32_f16(a[m], b[n], acc[m][n], 0,0,0);
        }

        #pragma unroll
        for (int m=0;m<4;++m) {
            #pragma unroll
            for (int r=0;r<4;++r) {
                int grow = m0 + wr*64 + m*16 + l4*4 + r;
                int b_   = grow >> 11;
                int lrow = grow & (Lq-1);
                #pragma unroll
                for (int n=0;n<4;++n) {
                    int gcol = n0 + wc*64 + n*16 + l15;
                    int h = gcol >> 6, d = gcol & 63;
                    int bh = b_*Hq + h;
                    f16 val = (f16)acc[m][n][r];
                    if (z==0)      q_h[((size_t)bh*Lq + lrow)*HDq + d] = val;
                    else if (z==1) k_h[((size_t)bh*Lq + lrow)*HDq + d] = val;
                    else           vT_h[((size_t)bh*HDq + d)*Lq + lrow] = val;
                }
            }
        }
    } else {
        // ---------------- quantum transpose block ----------------
        float (*qs)[64] = (float(*)[64])smem;
        const int q  = id - 768;
        const int qt = q & 63;
        const int kt = (q >> 6) & 31;
        const int b  = q >> 11;
        const float* base = quantum + ((size_t)b*Lq + qt*32)*Lq + kt*64;
        #pragma unroll
        for (int i=0;i<2;++i) {
            int idx = tid + i*256;
            int r = idx >> 4, c = (idx & 15)*4;
            float4 v = *reinterpret_cast<const float4*>(base + (size_t)r*Lq + c);
            qs[r][c]=v.x; qs[r][c+1]=v.y; qs[r][c+2]=v.z; qs[r][c+3]=v.w;
        }
        __syncthreads();
        const int seg = tid >> 6, lane = tid & 63, l31 = lane & 31, hi = lane >> 5;
        f16x8 u;
        #pragma unroll
        for (int e=0;e<8;++e) {
            int key = 16*seg + 8*(e>>2) + 4*hi + (e&3);
            u[e] = (f16)qs[l31][key];
        }
        f16* outp = qm_pre + (((size_t)b*32 + kt)*64 + qt)*2048 + seg*512 + lane*8;
        *reinterpret_cast<f16x8*>(outp) = u;
    }
}

// ---- flash attention: 2-tile software-pipelined epochs (QK,QK,SMPV,SMPV) ----
__global__ __launch_bounds__(256, 2) void attn4_kernel(
    const f16* __restrict__ q_h, const f16* __restrict__ k_h, const f16* __restrict__ vT_h,
    const f16* __restrict__ qm_pre, const float* __restrict__ scale,
    float* __restrict__ out)
{
    __shared__ __align__(16) char lds[65536];   // 4 quarters x [K 8KB | V 8KB]

    const int tid  = threadIdx.x;
    const int lane = tid & 63;
    const int wave = tid >> 6;          // 0..3
    const int l31  = lane & 31;
    const int hi   = lane >> 5;
    const int bh = blockIdx.x;
    const int qb = blockIdx.y;
    const int b_ = bh >> 4, h = bh & 15;
    const int qW = qb*128 + wave*32;
    const int qt = qb*4 + wave;
    const float sc = scale[h];
    const float c1 = 0.125f * sc * 1.44269504f;
    const float c2 = sc * 1.44269504f;

    const f16* kbase = k_h  + (size_t)bh*Lq*HDq;
    const f16* vbase = vT_h + (size_t)bh*HDq*Lq;

    f16x8 qf[4];
    {
        const f16* qb_ = q_h + ((size_t)bh*Lq + qW + l31)*HDq + hi*8;
        #pragma unroll
        for (int ds=0; ds<4; ++ds)
            qf[ds] = *reinterpret_cast<const f16x8*>(qb_ + ds*16);
    }

    f32x16 o0, o1;
    #pragma unroll
    for (int r=0;r<16;++r) { o0[r]=0.f; o1[r]=0.f; }
    float m_run = -1e30f, s_run = 0.f;

    // tile t (0..31) lives in quarter ((t>>1)&1)*2 + (t&1)
    auto QTR = [](int t) { return ((t >> 1) & 1)*2 + (t & 1); };

    auto STAGE = [&](int t) {
        const int k0 = t*64;
        char* LK = lds + QTR(t)*16384;
        char* LV = LK + 8192;
        #pragma unroll
        for (int i=0;i<2;++i) {
            int g = tid + i*256;
            int row = g >> 3, slot = g & 7;
            int ss = slot ^ (row & 7);
            gload_lds16(kbase + (size_t)(k0+row)*HDq + ss*8, LK + g*16);
            gload_lds16(vbase + (size_t)row*Lq + k0 + ss*8,  LV + g*16);
        }
    };

    auto QMLOAD = [&](int t, f16x8 (&qm)[4]) {
        const f16* qmb = qm_pre + (((size_t)b_*32 + t)*64 + qt)*2048 + lane*8;
        #pragma unroll
        for (int s=0;s<4;++s)
            qm[s] = *reinterpret_cast<const f16x8*>(qmb + s*512);
    };

    // QK^T only: st = K Q^T for tile t (no dependence on softmax state)
    auto QK = [&](int t, f32x16 (&st)[2]) {
        const char* LK = lds + QTR(t)*16384;
        __builtin_amdgcn_s_setprio(1);
        #pragma unroll
        for (int kt=0;kt<2;++kt) {
            #pragma unroll
            for (int r=0;r<16;++r) st[kt][r]=0.f;
            #pragma unroll
            for (int ds=0;ds<4;++ds) {
                f16x8 ka = *reinterpret_cast<const f16x8*>(
                    LK + ((kt*32+l31)<<7) + (((ds*2+hi)^(l31&7))<<4));
                st[kt] = __builtin_amdgcn_mfma_f32_32x32x16_f16(ka, qf[ds], st[kt], 0,0,0);
            }
        }
        __builtin_amdgcn_s_setprio(0);
    };

    // softmax + PV for tile t (consumes st, qmc)
    auto SMPV = [&](int t, f32x16 (&st)[2], f16x8 (&qmc)[4]) {
        const char* LV = lds + QTR(t)*16384 + 8192;

        float lg[32];
        #pragma unroll
        for (int s=0;s<4;++s)
            #pragma unroll
            for (int e=0;e<8;++e) {
                int i = s*8 + e;
                float sv = (i < 16) ? st[0][i] : st[1][i-16];
                lg[i] = sv*c1 + (float)qmc[s][e]*c2;
            }

        float tm[16];
        #pragma unroll
        for (int r=0;r<16;++r) tm[r] = fmaxf(lg[r], lg[r+16]);
        #pragma unroll
        for (int w=8; w>0; w>>=1)
            #pragma unroll
            for (int r=0;r<w;++r) tm[r] = fmaxf(tm[r], tm[r+w]);
        float tmax = fmaxf(tm[0], __shfl_xor(tm[0], 32));

        if (!__all(tmax <= m_run + 8.f)) {
            float m_new = fmaxf(m_run, tmax);
            float corr = __builtin_amdgcn_exp2f(m_run - m_new);
            m_run = m_new;
            s_run *= corr;
            #pragma unroll
            for (int r=0;r<16;++r) { o0[r] *= corr; o1[r] *= corr; }
        }

        float p[32];
        #pragma unroll
        for (int r=0;r<32;++r) p[r] = __builtin_amdgcn_exp2f(lg[r] - m_run);
        float sm[16];
        #pragma unroll
        for (int r=0;r<16;++r) sm[r] = p[r] + p[r+16];
        #pragma unroll
        for (int w=8; w>0; w>>=1)
            #pragma unroll
            for (int r=0;r<w;++r) sm[r] += sm[r+w];
        s_run += sm[0];

        f16x8 pb[4];
        #pragma unroll
        for (int ks=0; ks<4; ++ks) {
            int w0 = pk2(p[8*ks+0], p[8*ks+1]);
            int w1 = pk2(p[8*ks+2], p[8*ks+3]);
            int w2 = pk2(p[8*ks+4], p[8*ks+5]);
            int w3 = pk2(p[8*ks+6], p[8*ks+7]);
            swap32(w0, w2);
            swap32(w1, w3);
            union { int w[4]; f16x8 v; } u;
            u.w[0]=w0; u.w[1]=w1; u.w[2]=w2; u.w[3]=w3;
            pb[ks] = u.v;
        }

        __builtin_amdgcn_s_setprio(1);
        #pragma unroll
        for (int ks=0; ks<4; ++ks) {
            f16x8 va0 = *reinterpret_cast<const f16x8*>(
                LV + (l31<<7)        + (((ks*2+hi)^(l31&7))<<4));
            f16x8 va1 = *reinterpret_cast<const f16x8*>(
                LV + ((32+l31)<<7)   + (((ks*2+hi)^(l31&7))<<4));
            o0 = __builtin_amdgcn_mfma_f32_32x32x16_f16(va0, pb[ks], o0, 0,0,0);
            o1 = __builtin_amdgcn_mfma_f32_32x32x16_f16(va1, pb[ks], o1, 0,0,0);
        }
        __builtin_amdgcn_s_setprio(0);
    };

    f16x8 qmE[4], qmO[4];
    f32x16 stA[2], stB[2];

    // prologue: qm(0),qm(1) + epoch-0 tiles (quarters 0,1)
    QMLOAD(0, qmE);
    QMLOAD(1, qmO);
    STAGE(0); STAGE(1);

    #define VMW(n) asm volatile("s_waitcnt vmcnt(" #n ")" ::: "memory")

    // one barrier per 128-key epoch, at epoch END.
    // Epoch e: stage tiles 2e+2,2e+3 (other buffer pair), QK both current
    // tiles before any softmax (MFMA pipe loaded while SM runs), then
    // SMPV both; qm refilled right after its consumer.
    // vmcnt at epoch end: younger-than-stages = 8 qm refills -> VMW(8).
    VMW(0); __builtin_amdgcn_s_barrier();
    for (int e = 0; e < 15; ++e) {
        STAGE(2*e+2); STAGE(2*e+3);
        QK(2*e,   stA);
        QK(2*e+1, stB);
        SMPV(2*e,   stA, qmE);  QMLOAD(2*e+2, qmE);
        SMPV(2*e+1, stB, qmO);  QMLOAD(2*e+3, qmO);
        VMW(8); __builtin_amdgcn_s_barrier();
    }
    // epoch 15: tiles 30,31; no further stage/refill
    QK(30, stA);
    QK(31, stB);
    SMPV(30, stA, qmE);
    SMPV(31, stB, qmO);

    #undef VMW

    // epilogue
    float s_tot = s_run + __shfl_xor(s_run, 32);
    float inv = 1.0f / s_tot;
    float* ob = out + ((size_t)b_*Lq + qW + l31)*Dq + h*HDq;
    #pragma unroll
    for (int r=0;r<16;++r) {
        int drow = (r&3) + 8*(r>>2) + 4*hi;
        ob[drow]      = o0[r]*inv;
        ob[32 + drow] = o1[r]*inv;
    }
}

extern "C" void kernel_launch(void* const* d_in, const int* in_sizes, int n_in,
                              void* d_out, int out_size, void* d_ws, size_t ws_size,
                              hipStream_t stream) {
    const float* x       = (const float*)d_in[0];
    const float* quantum = (const float*)d_in[1];
    const float* wq      = (const float*)d_in[2];
    const float* wk      = (const float*)d_in[3];
    const float* wv      = (const float*)d_in[4];
    const float* scale   = (const float*)d_in[5];
    float* out = (float*)d_out;

    f16* ws     = (f16*)d_ws;
    f16* x_h    = ws;
    f16* wq_h   = ws + 4194304;
    f16* wk_h   = ws + 5242880;
    f16* wv_h   = ws + 6291456;
    f16* q_h    = ws + 7340032;
    f16* k_h    = ws + 11534336;
    f16* vT_h   = ws + 15728640;
    f16* qm_pre = ws + 19922944;

    convert_kernel<<<1024, 256, 0, stream>>>(x, wq, wk, wv, x_h, wq_h, wk_h, wv_h);

    qkv_qm_fused_kernel<<<4864, 256, 0, stream>>>(
        x_h, wq_h, wk_h, wv_h, quantum, q_h, k_h, vT_h, qm_pre);

    dim3 g2(Bq*Hq, Lq/128);
    attn4_kernel<<<g2, 256, 0, stream>>>(q_h, k_h, vT_h, qm_pre, scale, out);
}